// Round 16
// baseline (597.841 us; speedup 1.0000x reference)
//
#include <hip/hip_runtime.h>

#define NB 8
#define TT 8192
#define NN 256
#define CH 64             // chunk length (== GEMM M-tile)
#define BT (NB*TT)        // 65536 rows total
#define NCHUNK (BT/CH)    // 1024
#define GPB (TT/CH)       // 128 chunks per sequence
#define SENTINEL 0xFFFFFFFFFFFFFFFFull

typedef float f4 __attribute__((ext_vector_type(4)));
typedef unsigned u4 __attribute__((ext_vector_type(4)));
typedef short b8 __attribute__((ext_vector_type(8)));
typedef unsigned long long u64;

static __device__ __forceinline__ ushort f2bf(float f) {
  union { float f; unsigned u; } v; v.f = f;
  return (ushort)((v.u + 0x7fffu + ((v.u >> 16) & 1u)) >> 16);  // RNE
}
static __device__ __forceinline__ float bf2f(ushort h) {
  union { unsigned u; float f; } v; v.u = ((unsigned)h) << 16; return v.f;
}

// ---------------- setup: weights (verbatim R9) + Pow table + payload sentinel-clear ----
// Pow[(j-1)*NN + m] = L^j for j = 1..64  (L = Pow[0], L^64 = Pow[63*NN])
__global__ void k_setup(const float* __restrict__ nu_log, const float* __restrict__ theta_log,
                        const float* __restrict__ gamma_log,
                        const float* __restrict__ B_re, const float* __restrict__ B_im,
                        const float* __restrict__ C_re, const float* __restrict__ C_im,
                        float2* __restrict__ Pow, unsigned* __restrict__ ticket,
                        u64* __restrict__ payload,
                        ushort* __restrict__ BnRe, ushort* __restrict__ BnIm,
                        ushort* __restrict__ CRe, ushort* __restrict__ CIm) {
  int bid = blockIdx.x, tid = threadIdx.x;
  // every block clears a slice of payload to SENTINEL (262144 u64 total)
  for (int k = 0; k < 4; ++k) {
    int idx = (bid * 256 + tid) * 4 + k;
    if (idx < NCHUNK * NN) payload[idx] = SENTINEL;
  }
  if (bid < NN) {
    int m = bid, n = tid;
    float g = expf(gamma_log[m]);
    int idx = m * NN + n;
    BnRe[idx] = f2bf(B_re[idx] * g);
    BnIm[idx] = f2bf(B_im[idx] * g);
    CRe[idx]  = f2bf(C_re[idx]);
    CIm[idx]  = f2bf(-C_im[idx]);   // pre-negated so GEMM2 is pure accumulate
  } else {
    if (tid == 0) *ticket = 0;
    int m = tid;
    float Lmod = expf(-expf(nu_log[m]));
    float th = expf(theta_log[m]);
    float lre = Lmod * cosf(th), lim = Lmod * sinf(th);
    float pr = 1.f, pi = 0.f;                 // L^0
    for (int j = 1; j <= CH; ++j) {
      float npr = pr * lre - pi * lim;
      pi = pr * lim + pi * lre;
      pr = npr;                               // now L^j
      Pow[(size_t)(j - 1) * NN + m] = make_float2(pr, pi);
    }
  }
}

// ---- stage 64x256 fp32 x tile into LDS (64 KB), coalesced, swizzled (VERBATIM R11) ----
static __device__ __forceinline__ void stage_x_f32(const float* __restrict__ xt,
                                                   char* lds, int tid) {
#pragma unroll
  for (int i = 0; i < 16; ++i) {
    int fi = i * 1024 + tid * 4;               // float index in 64x256 tile
    f4 w = *(const f4*)(xt + fi);              // wave reads 1 KB contiguous
    int r = fi >> 8, c = fi & 255;
    int dst = r * 1024 + ((c * 4) ^ ((r & 7) << 4));
    *(f4*)(lds + dst) = w;
  }
}

// ---- GEMM1 from staged fp32 LDS tile: acc[4][4] complex (VERBATIM R11) ----
static __device__ __forceinline__ void gemm1_ldsx(const char* lds,
                                                  const ushort* __restrict__ BnRe,
                                                  const ushort* __restrict__ BnIm,
                                                  int tid, f4 accRe[4][4], f4 accIm[4][4]) {
  int lane = tid & 63, wid = tid >> 6;
  int lr = lane & 15, lg = lane >> 4;
  int mq = wid * 64;
  for (int ks = 0; ks < 8; ++ks) {
    int k0 = ks * 32 + lg * 8;
    b8 a[4];
    for (int mf = 0; mf < 4; ++mf) {
      int r = mf * 16 + lr;
      int sw = (r & 7) << 4;
      const char* base = lds + r * 1024;
      f4 x0 = *(const f4*)(base + ((k0 * 4) ^ sw));
      f4 x1 = *(const f4*)(base + ((k0 * 4 + 16) ^ sw));
      b8 t;
      t[0] = (short)f2bf(x0[0]); t[1] = (short)f2bf(x0[1]);
      t[2] = (short)f2bf(x0[2]); t[3] = (short)f2bf(x0[3]);
      t[4] = (short)f2bf(x1[0]); t[5] = (short)f2bf(x1[1]);
      t[6] = (short)f2bf(x1[2]); t[7] = (short)f2bf(x1[3]);
      a[mf] = t;
    }
    for (int nf = 0; nf < 4; ++nf) {
      int mrow = mq + nf * 16 + lr;
      b8 br = *(const b8*)(BnRe + (size_t)mrow * NN + k0);
      b8 bi = *(const b8*)(BnIm + (size_t)mrow * NN + k0);
      for (int mf = 0; mf < 4; ++mf) {
        accRe[mf][nf] = __builtin_amdgcn_mfma_f32_16x16x32_bf16(a[mf], br, accRe[mf][nf], 0, 0, 0);
        accIm[mf][nf] = __builtin_amdgcn_mfma_f32_16x16x32_bf16(a[mf], bi, accIm[mf][nf], 0, 0, 0);
      }
    }
  }
}

// ---------------- FUSED: ticket -> stage -> GEMM1 -> reduce -> chain -> scan -> GEMM2 ----
__global__ __launch_bounds__(256) void k_fused(const float* __restrict__ x,
                                               const ushort* __restrict__ BnRe,
                                               const ushort* __restrict__ BnIm,
                                               const ushort* __restrict__ CRe,
                                               const ushort* __restrict__ CIm,
                                               const float2* __restrict__ Pow,
                                               unsigned* ticket, u64* payload,
                                               float* __restrict__ out) {
  __shared__ char lds[CH * 1024];
  __shared__ int s_cid;
  int tid = threadIdx.x;
  int lane = tid & 63, wid = tid >> 6;
  int lr = lane & 15, lg = lane >> 4;
  int mq = wid * 64;

  if (tid == 0)
    s_cid = (int)(__hip_atomic_fetch_add(ticket, 1u, __ATOMIC_RELAXED,
                                         __HIP_MEMORY_SCOPE_AGENT) & (NCHUNK - 1));
  __syncthreads();
  int cid = s_cid;
  int g = cid & (GPB - 1);
  size_t rowbase = (size_t)cid * CH;

  stage_x_f32(x + rowbase * NN, lds, tid);
  __syncthreads();

  f4 accRe[4][4], accIm[4][4];
  for (int i = 0; i < 4; ++i)
    for (int j = 0; j < 4; ++j) { accRe[i][j] = (f4)0.f; accIm[i][j] = (f4)0.f; }
  gemm1_ldsx(lds, BnRe, BnIm, tid, accRe, accIm);

  // local carry: lc[nf] = sum_t L^(63-t) * Bu[t][col]  (R9-verbatim; butterfly -> all lanes)
  float lcr[4], lci[4];
  for (int nf = 0; nf < 4; ++nf) {
    int col = mq + nf * 16 + lr;
    float sr = 0.f, si = 0.f;
    for (int mf = 0; mf < 4; ++mf)
      for (int q = 0; q < 4; ++q) {
        int t = mf * 16 + lg * 4 + q;
        float2 w = (t == CH - 1) ? make_float2(1.f, 0.f)
                                 : Pow[(size_t)(CH - 2 - t) * NN + col];  // L^(63-t)
        float br = accRe[mf][nf][q], bi = accIm[mf][nf][q];
        sr += w.x * br - w.y * bi;
        si += w.x * bi + w.y * br;
      }
    sr += __shfl_xor(sr, 16, 64);  si += __shfl_xor(si, 16, 64);
    sr += __shfl_xor(sr, 32, 64);  si += __shfl_xor(si, 32, 64);
    lcr[nf] = sr; lci[nf] = si;
  }

  // chain: spin on predecessor's inclusive prefix for THIS thread's channel
  float2 seed = make_float2(0.f, 0.f);
  if (g > 0) {
    u64 v; int it = 0;
    do {
      v = __hip_atomic_load(&payload[(size_t)(cid - 1) * NN + tid],
                            __ATOMIC_RELAXED, __HIP_MEMORY_SCOPE_AGENT);
      if (v != SENTINEL) break;
      __builtin_amdgcn_s_sleep(2);
    } while (++it < (1 << 24));                // failsafe: loud fail, no hang
    union { u64 u; float2 f; } cv; cv.u = v;
    seed = cv.f;
  }

  // publish inclusive[cid] = L^64 * seed + local  (lg==0 lanes; wave-local shfl for seeds)
  if (g < GPB - 1) {
    for (int nf = 0; nf < 4; ++nf) {
      int col = mq + nf * 16 + lr;
      float sx = __shfl(seed.x, col & 63, 64);
      float sy = __shfl(seed.y, col & 63, 64);
      if (lg == 0) {
        float2 LC = Pow[(size_t)(CH - 1) * NN + col];   // L^64
        union { float2 f; u64 u; } ov;
        ov.f = make_float2(LC.x * sx - LC.y * sy + lcr[nf],
                           LC.x * sy + LC.y * sx + lci[nf]);
        __hip_atomic_store(&payload[(size_t)cid * NN + col], ov.u,
                           __ATOMIC_RELAXED, __HIP_MEMORY_SCOPE_AGENT);
      }
    }
  }
  __syncthreads();   // all GEMM1 LDS reads done before Bu overwrites the x tile

  for (int mf = 0; mf < 4; ++mf)      // packed Bu store (VERBATIM R11)
    for (int nf = 0; nf < 4; ++nf)
      for (int r = 0; r < 4; ++r) {
        int row = mf * 16 + lg * 4 + r;
        int col = mq + nf * 16 + lr;
        unsigned p = (unsigned)f2bf(accRe[mf][nf][r]) | ((unsigned)f2bf(accIm[mf][nf][r]) << 16);
        int off = row * 1024 + ((col * 4) ^ ((row & 7) << 4));
        *(unsigned*)(lds + off) = p;
      }
  __syncthreads();

  { // seeded scan, in place (packed Bu -> packed h), VERBATIM R11; L = Pow[0] = L^1
    int c = tid;
    float2 L = Pow[c];
    float hr = seed.x, hi = seed.y;
    for (int k = 0; k < CH; ++k) {
      int off = k * 1024 + ((c * 4) ^ ((k & 7) << 4));
      unsigned u = *(const unsigned*)(lds + off);
      float ur = bf2f((ushort)(u & 0xffffu)), ui = bf2f((ushort)(u >> 16));
      float nr = L.x * hr - L.y * hi + ur;
      hi = L.x * hi + L.y * hr + ui;
      hr = nr;
      *(unsigned*)(lds + off) = (unsigned)f2bf(hr) | ((unsigned)f2bf(hi) << 16);
    }
  }
  __syncthreads();

  // GEMM2: out[t][m] = hRe·CRe + hIm·(-CIm)  (VERBATIM R11)
  f4 acc[4][4];
  for (int i = 0; i < 4; ++i)
    for (int j = 0; j < 4; ++j) acc[i][j] = (f4)0.f;

  for (int ks = 0; ks < 8; ++ks) {
    int k0 = ks * 32 + lg * 8;
    b8 ar[4], ai[4];
    for (int mf = 0; mf < 4; ++mf) {
      int row = mf * 16 + lr;
      int m4 = (row & 7) << 4;
      const char* base = lds + row * 1024;
      u4 p0 = *(const u4*)(base + ((k0 * 4) ^ m4));
      u4 p1 = *(const u4*)(base + ((k0 * 4 + 16) ^ m4));
      b8 tr, ti;
      tr[0] = (short)(p0[0] & 0xffffu); ti[0] = (short)(p0[0] >> 16);
      tr[1] = (short)(p0[1] & 0xffffu); ti[1] = (short)(p0[1] >> 16);
      tr[2] = (short)(p0[2] & 0xffffu); ti[2] = (short)(p0[2] >> 16);
      tr[3] = (short)(p0[3] & 0xffffu); ti[3] = (short)(p0[3] >> 16);
      tr[4] = (short)(p1[0] & 0xffffu); ti[4] = (short)(p1[0] >> 16);
      tr[5] = (short)(p1[1] & 0xffffu); ti[5] = (short)(p1[1] >> 16);
      tr[6] = (short)(p1[2] & 0xffffu); ti[6] = (short)(p1[2] >> 16);
      tr[7] = (short)(p1[3] & 0xffffu); ti[7] = (short)(p1[3] >> 16);
      ar[mf] = tr; ai[mf] = ti;
    }
    for (int nf = 0; nf < 4; ++nf) {
      int m = mq + nf * 16 + lr;
      b8 cr = *(const b8*)(CRe + (size_t)m * NN + k0);
      b8 ci = *(const b8*)(CIm + (size_t)m * NN + k0);
      for (int mf = 0; mf < 4; ++mf) {
        acc[mf][nf] = __builtin_amdgcn_mfma_f32_16x16x32_bf16(ar[mf], cr, acc[mf][nf], 0, 0, 0);
        acc[mf][nf] = __builtin_amdgcn_mfma_f32_16x16x32_bf16(ai[mf], ci, acc[mf][nf], 0, 0, 0);
      }
    }
  }
  for (int mf = 0; mf < 4; ++mf)
    for (int nf = 0; nf < 4; ++nf)
      for (int r = 0; r < 4; ++r) {
        size_t t = rowbase + mf * 16 + lg * 4 + r;
        out[t * NN + mq + nf * 16 + lr] = acc[mf][nf][r];
      }
}

extern "C" void kernel_launch(void* const* d_in, const int* in_sizes, int n_in,
                              void* d_out, int out_size, void* d_ws, size_t ws_size,
                              hipStream_t stream) {
  const float* x         = (const float*)d_in[0];
  const float* nu_log    = (const float*)d_in[1];
  const float* theta_log = (const float*)d_in[2];
  const float* gamma_log = (const float*)d_in[3];
  const float* B_re      = (const float*)d_in[4];
  const float* B_im      = (const float*)d_in[5];
  const float* C_re      = (const float*)d_in[6];
  const float* C_im      = (const float*)d_in[7];
  float* out = (float*)d_out;

  // d_ws usage: 2,752,768 bytes — below the proven 2,756,608 ceiling.
  char* ws = (char*)d_ws;
  u64*      payload = (u64*)(ws + 0);            // 1024*256*8 = 2,097,152
  unsigned* ticket  = (unsigned*)(ws + 2097152); // 4 (padded to 256)
  float2*   Pow     = (float2*)(ws + 2097408);   // 64*256*8 = 131,072
  ushort*   BnRe    = (ushort*)(ws + 2228480);   // 131,072
  ushort*   BnIm    = (ushort*)(ws + 2359552);   // 131,072
  ushort*   CRe     = (ushort*)(ws + 2490624);   // 131,072
  ushort*   CIm     = (ushort*)(ws + 2621696);   // 131,072  (end 2,752,768)

  hipLaunchKernelGGL(k_setup, dim3(NN + 1), dim3(NN), 0, stream,
                     nu_log, theta_log, gamma_log, B_re, B_im, C_re, C_im,
                     Pow, ticket, payload, BnRe, BnIm, CRe, CIm);
  hipLaunchKernelGGL(k_fused, dim3(NCHUNK), dim3(256), 0, stream,
                     x, BnRe, BnIm, CRe, CIm, Pow, ticket, payload, out);
}

// Round 17
// 177.059 us; speedup vs baseline: 3.3765x; 3.3765x over previous
//
#include <hip/hip_runtime.h>

#define NB 8
#define TT 8192
#define NN 256
#define CH 64             // chunk length (== GEMM M-tile)
#define BT (NB*TT)        // 65536 rows total
#define NCHUNK (BT/CH)    // 1024
#define GPB (TT/CH)       // 128 chunks per sequence

typedef float f4 __attribute__((ext_vector_type(4)));
typedef unsigned u4 __attribute__((ext_vector_type(4)));
typedef short b8 __attribute__((ext_vector_type(8)));

static __device__ __forceinline__ ushort f2bf(float f) {
  union { float f; unsigned u; } v; v.f = f;
  return (ushort)((v.u + 0x7fffu + ((v.u >> 16) & 1u)) >> 16);  // RNE
}
static __device__ __forceinline__ float bf2f(ushort h) {
  union { unsigned u; float f; } v; v.u = ((unsigned)h) << 16; return v.f;
}

// ---------------- setup: params + bf16 weight copies + Lpow table (VERBATIM R9/R11) ----
__global__ void k_setup(const float* __restrict__ nu_log, const float* __restrict__ theta_log,
                        const float* __restrict__ gamma_log,
                        const float* __restrict__ B_re, const float* __restrict__ B_im,
                        const float* __restrict__ C_re, const float* __restrict__ C_im,
                        float2* __restrict__ Lc, float2* __restrict__ LCH,
                        float2* __restrict__ Lpow,
                        ushort* __restrict__ BnRe, ushort* __restrict__ BnIm,
                        ushort* __restrict__ CRe, ushort* __restrict__ CIm) {
  int bid = blockIdx.x, tid = threadIdx.x;
  if (bid < NN) {
    int m = bid, n = tid;
    float g = expf(gamma_log[m]);
    int idx = m * NN + n;
    BnRe[idx] = f2bf(B_re[idx] * g);
    BnIm[idx] = f2bf(B_im[idx] * g);
    CRe[idx]  = f2bf(C_re[idx]);
    CIm[idx]  = f2bf(-C_im[idx]);   // pre-negated so GEMM2 is pure accumulate
  } else {
    int m = tid;
    float Lmod = expf(-expf(nu_log[m]));
    float th = expf(theta_log[m]);
    float lre = Lmod * cosf(th), lim = Lmod * sinf(th);
    Lc[m] = make_float2(lre, lim);
    float pr = 1.f, pi = 0.f;
    for (int k = 0; k < CH; ++k) {
      // Lpow[t][m] = L^(CH-1-t): weight of Bu[t] in the chunk carry
      Lpow[(size_t)(CH - 1 - k) * NN + m] = make_float2(pr, pi);  // L^k
      float npr = pr * lre - pi * lim;
      pi = pr * lim + pi * lre;
      pr = npr;
    }
    LCH[m] = make_float2(pr, pi);   // L^CH
  }
}

// ---- stage 64x256 fp32 x tile into LDS (64 KB), coalesced, swizzled (VERBATIM R11) ----
static __device__ __forceinline__ void stage_x_f32(const float* __restrict__ xt,
                                                   char* lds, int tid) {
#pragma unroll
  for (int i = 0; i < 16; ++i) {
    int fi = i * 1024 + tid * 4;               // float index in 64x256 tile
    f4 w = *(const f4*)(xt + fi);              // wave reads 1 KB contiguous
    int r = fi >> 8, c = fi & 255;
    int dst = r * 1024 + ((c * 4) ^ ((r & 7) << 4));
    *(f4*)(lds + dst) = w;
  }
}

// ---- GEMM1 from staged fp32 LDS tile: acc[4][4] complex (VERBATIM R11) ----
static __device__ __forceinline__ void gemm1_ldsx(const char* lds,
                                                  const ushort* __restrict__ BnRe,
                                                  const ushort* __restrict__ BnIm,
                                                  int tid, f4 accRe[4][4], f4 accIm[4][4]) {
  int lane = tid & 63, wid = tid >> 6;
  int lr = lane & 15, lg = lane >> 4;
  int mq = wid * 64;
  for (int ks = 0; ks < 8; ++ks) {
    int k0 = ks * 32 + lg * 8;
    b8 a[4];
    for (int mf = 0; mf < 4; ++mf) {
      int r = mf * 16 + lr;
      int sw = (r & 7) << 4;
      const char* base = lds + r * 1024;
      f4 x0 = *(const f4*)(base + ((k0 * 4) ^ sw));
      f4 x1 = *(const f4*)(base + ((k0 * 4 + 16) ^ sw));
      b8 t;
      t[0] = (short)f2bf(x0[0]); t[1] = (short)f2bf(x0[1]);
      t[2] = (short)f2bf(x0[2]); t[3] = (short)f2bf(x0[3]);
      t[4] = (short)f2bf(x1[0]); t[5] = (short)f2bf(x1[1]);
      t[6] = (short)f2bf(x1[2]); t[7] = (short)f2bf(x1[3]);
      a[mf] = t;
    }
    for (int nf = 0; nf < 4; ++nf) {
      int mrow = mq + nf * 16 + lr;
      b8 br = *(const b8*)(BnRe + (size_t)mrow * NN + k0);
      b8 bi = *(const b8*)(BnIm + (size_t)mrow * NN + k0);
      for (int mf = 0; mf < 4; ++mf) {
        accRe[mf][nf] = __builtin_amdgcn_mfma_f32_16x16x32_bf16(a[mf], br, accRe[mf][nf], 0, 0, 0);
        accIm[mf][nf] = __builtin_amdgcn_mfma_f32_16x16x32_bf16(a[mf], bi, accIm[mf][nf], 0, 0, 0);
      }
    }
  }
}

// ---------------- K1: stage x -> GEMM1(LDS) -> Lpow reduce -> carry (VERBATIM R11) ----
__global__ __launch_bounds__(256) void k_carry(const float* __restrict__ x,
                                               const ushort* __restrict__ BnRe,
                                               const ushort* __restrict__ BnIm,
                                               const float2* __restrict__ Lpow,
                                               float2* __restrict__ carry) {
  __shared__ char lds[65536];
  int cid = blockIdx.x, tid = threadIdx.x;
  int lane = tid & 63, wid = tid >> 6;
  int lr = lane & 15, lg = lane >> 4;
  int mq = wid * 64;

  stage_x_f32(x + (size_t)cid * CH * NN, lds, tid);
  __syncthreads();

  f4 accRe[4][4], accIm[4][4];
  for (int i = 0; i < 4; ++i)
    for (int j = 0; j < 4; ++j) { accRe[i][j] = (f4)0.f; accIm[i][j] = (f4)0.f; }
  gemm1_ldsx(lds, BnRe, BnIm, tid, accRe, accIm);

  for (int nf = 0; nf < 4; ++nf) {
    int col = mq + nf * 16 + lr;
    float sr = 0.f, si = 0.f;
    for (int mf = 0; mf < 4; ++mf)
      for (int q = 0; q < 4; ++q) {
        int t = mf * 16 + lg * 4 + q;
        float2 w = Lpow[(size_t)t * NN + col];
        float br = accRe[mf][nf][q], bi = accIm[mf][nf][q];
        sr += w.x * br - w.y * bi;
        si += w.x * bi + w.y * br;
      }
    sr += __shfl_xor(sr, 16, 64);  si += __shfl_xor(si, 16, 64);
    sr += __shfl_xor(sr, 32, 64);  si += __shfl_xor(si, 32, 64);
    if (lg == 0) carry[(size_t)cid * NN + col] = make_float2(sr, si);
  }
}

// ---------------- K2: scan carries across chunks, in place, load-pipelined (VERBATIM R11) ----
__global__ void k_seed(float2* __restrict__ carrySeed, const float2* __restrict__ LCH) {
  int b = blockIdx.x, m = threadIdx.x;
  float2 LC = LCH[m];
  float hr = 0.f, hi = 0.f;
  size_t base = (size_t)b * GPB * NN + m;
  float2 c = carrySeed[base];
  for (int g = 0; g < GPB; ++g) {
    size_t idx = base + (size_t)g * NN;
    float2 cn = (g + 1 < GPB) ? carrySeed[idx + NN] : make_float2(0.f, 0.f);
    carrySeed[idx] = make_float2(hr, hi);     // exclusive prefix -> seed
    float nr = LC.x * hr - LC.y * hi + c.x;
    hi = LC.x * hi + LC.y * hr + c.y;
    hr = nr;
    c = cn;
  }
}

// ---------------- K3: stage -> GEMM1 -> REGISTER SCAN -> h pack -> GEMM2 -> out ----
// Scan done in registers on the fp32 accumulators (segmented: 4-row intra-lane scans,
// cross-lg shfl combine with L^4/L^8, in-lane quarter+seed combine with L^16).
__global__ __launch_bounds__(256) void k_out(const float* __restrict__ x,
                                             const ushort* __restrict__ BnRe,
                                             const ushort* __restrict__ BnIm,
                                             const float2* __restrict__ Lc,
                                             const float2* __restrict__ seed,
                                             const ushort* __restrict__ CRe,
                                             const ushort* __restrict__ CIm,
                                             const float2* __restrict__ Lpow,
                                             float* __restrict__ out) {
  __shared__ char lds[65536];
  int cid = blockIdx.x, tid = threadIdx.x;
  size_t rowbase = (size_t)cid * CH;
  int lane = tid & 63, wid = tid >> 6;
  int lr = lane & 15, lg = lane >> 4;
  int mq = wid * 64;

  stage_x_f32(x + rowbase * NN, lds, tid);
  __syncthreads();

  f4 accRe[4][4], accIm[4][4];
  for (int i = 0; i < 4; ++i)
    for (int j = 0; j < 4; ++j) { accRe[i][j] = (f4)0.f; accIm[i][j] = (f4)0.f; }
  gemm1_ldsx(lds, BnRe, BnIm, tid, accRe, accIm);

  // ---- register scan: acc (Bu) -> acc (h), per channel col = mq + nf*16 + lr ----
  // L^j = Lpow[(CH-1-j)*NN + c]
  for (int nf = 0; nf < 4; ++nf) {
    int c = mq + nf * 16 + lr;
    float2 L1  = Lc[c];
    float2 L4  = Lpow[(size_t)(CH - 1 - 4)  * NN + c];
    float2 L8  = Lpow[(size_t)(CH - 1 - 8)  * NN + c];
    float2 L16 = Lpow[(size_t)(CH - 1 - 16) * NN + c];
    float2 w4  = (lg == 0) ? make_float2(1.f, 0.f)
                           : Lpow[(size_t)(CH - 1 - 4 * lg) * NN + c];  // L^(4lg)
    float2 sd  = seed[(size_t)cid * NN + c];

    float Cr[4], Ci[4];
    for (int mf = 0; mf < 4; ++mf) {       // intra-lane inclusive 4-scan (in place)
      for (int q = 1; q < 4; ++q) {
        float sr_ = L1.x * accRe[mf][nf][q-1] - L1.y * accIm[mf][nf][q-1] + accRe[mf][nf][q];
        float si_ = L1.x * accIm[mf][nf][q-1] + L1.y * accRe[mf][nf][q-1] + accIm[mf][nf][q];
        accRe[mf][nf][q] = sr_; accIm[mf][nf][q] = si_;
      }
      Cr[mf] = accRe[mf][nf][3]; Ci[mf] = accIm[mf][nf][3];
    }

    float Er[4], Ei[4], Qr[4], Qi[4];
    for (int mf = 0; mf < 4; ++mf) {       // cross-lg weighted scan (Hillis-Steele)
      float tx = __shfl_up(Cr[mf], 16, 64), ty = __shfl_up(Ci[mf], 16, 64);
      float m1 = (lg >= 1) ? 1.f : 0.f;
      float ax = Cr[mf] + m1 * (L4.x * tx - L4.y * ty);
      float ay = Ci[mf] + m1 * (L4.x * ty + L4.y * tx);
      float ux = __shfl_up(ax, 32, 64), uy = __shfl_up(ay, 32, 64);
      float m2 = (lg >= 2) ? 1.f : 0.f;
      float Ix = ax + m2 * (L8.x * ux - L8.y * uy);
      float Iy = ay + m2 * (L8.x * uy + L8.y * ux);
      float ex = __shfl_up(Ix, 16, 64), ey = __shfl_up(Iy, 16, 64);
      Er[mf] = m1 * ex; Ei[mf] = m1 * ey;
      Qr[mf] = __shfl(Ix, lr + 48, 64); Qi[mf] = __shfl(Iy, lr + 48, 64);  // quarter carry
    }

    float Hx = sd.x, Hy = sd.y;            // running scan value at quarter boundary
    for (int mf = 0; mf < 4; ++mf) {
      float Zx = Er[mf] + w4.x * Hx - w4.y * Hy;
      float Zy = Ei[mf] + w4.x * Hy + w4.y * Hx;
      float Wx = L1.x, Wy = L1.y;          // W = L^(q+1)
      for (int q = 0; q < 4; ++q) {
        float hr_ = accRe[mf][nf][q] + Wx * Zx - Wy * Zy;
        float hi_ = accIm[mf][nf][q] + Wx * Zy + Wy * Zx;
        accRe[mf][nf][q] = hr_; accIm[mf][nf][q] = hi_;
        if (q < 3) { float nWx = Wx * L1.x - Wy * L1.y; Wy = Wx * L1.y + Wy * L1.x; Wx = nWx; }
      }
      float nHx = Qr[mf] + L16.x * Hx - L16.y * Hy;
      Hy = Qi[mf] + L16.x * Hy + L16.y * Hx;
      Hx = nHx;
    }
  }
  __syncthreads();   // all GEMM1 LDS reads done before h overwrites the x tile

  for (int mf = 0; mf < 4; ++mf)      // packed h store (VERBATIM R11 Bu-store formula)
    for (int nf = 0; nf < 4; ++nf)
      for (int r = 0; r < 4; ++r) {
        int row = mf * 16 + lg * 4 + r;
        int col = mq + nf * 16 + lr;
        unsigned p = (unsigned)f2bf(accRe[mf][nf][r]) | ((unsigned)f2bf(accIm[mf][nf][r]) << 16);
        int off = row * 1024 + ((col * 4) ^ ((row & 7) << 4));
        *(unsigned*)(lds + off) = p;
      }
  __syncthreads();

  // GEMM2: out[t][m] = hRe·CRe + hIm·(-CIm)  (VERBATIM R11)
  f4 acc[4][4];
  for (int i = 0; i < 4; ++i)
    for (int j = 0; j < 4; ++j) acc[i][j] = (f4)0.f;

  for (int ks = 0; ks < 8; ++ks) {
    int k0 = ks * 32 + lg * 8;
    b8 ar[4], ai[4];
    for (int mf = 0; mf < 4; ++mf) {
      int row = mf * 16 + lr;
      int m4 = (row & 7) << 4;
      const char* base = lds + row * 1024;
      u4 p0 = *(const u4*)(base + ((k0 * 4) ^ m4));
      u4 p1 = *(const u4*)(base + ((k0 * 4 + 16) ^ m4));
      b8 tr, ti;
      tr[0] = (short)(p0[0] & 0xffffu); ti[0] = (short)(p0[0] >> 16);
      tr[1] = (short)(p0[1] & 0xffffu); ti[1] = (short)(p0[1] >> 16);
      tr[2] = (short)(p0[2] & 0xffffu); ti[2] = (short)(p0[2] >> 16);
      tr[3] = (short)(p0[3] & 0xffffu); ti[3] = (short)(p0[3] >> 16);
      tr[4] = (short)(p1[0] & 0xffffu); ti[4] = (short)(p1[0] >> 16);
      tr[5] = (short)(p1[1] & 0xffffu); ti[5] = (short)(p1[1] >> 16);
      tr[6] = (short)(p1[2] & 0xffffu); ti[6] = (short)(p1[2] >> 16);
      tr[7] = (short)(p1[3] & 0xffffu); ti[7] = (short)(p1[3] >> 16);
      ar[mf] = tr; ai[mf] = ti;
    }
    for (int nf = 0; nf < 4; ++nf) {
      int m = mq + nf * 16 + lr;
      b8 cr = *(const b8*)(CRe + (size_t)m * NN + k0);
      b8 ci = *(const b8*)(CIm + (size_t)m * NN + k0);
      for (int mf = 0; mf < 4; ++mf) {
        acc[mf][nf] = __builtin_amdgcn_mfma_f32_16x16x32_bf16(ar[mf], cr, acc[mf][nf], 0, 0, 0);
        acc[mf][nf] = __builtin_amdgcn_mfma_f32_16x16x32_bf16(ai[mf], ci, acc[mf][nf], 0, 0, 0);
      }
    }
  }
  for (int mf = 0; mf < 4; ++mf)
    for (int nf = 0; nf < 4; ++nf)
      for (int r = 0; r < 4; ++r) {
        size_t t = rowbase + mf * 16 + lg * 4 + r;
        out[t * NN + mq + nf * 16 + lr] = acc[mf][nf][r];
      }
}

extern "C" void kernel_launch(void* const* d_in, const int* in_sizes, int n_in,
                              void* d_out, int out_size, void* d_ws, size_t ws_size,
                              hipStream_t stream) {
  const float* x         = (const float*)d_in[0];
  const float* nu_log    = (const float*)d_in[1];
  const float* theta_log = (const float*)d_in[2];
  const float* gamma_log = (const float*)d_in[3];
  const float* B_re      = (const float*)d_in[4];
  const float* B_im      = (const float*)d_in[5];
  const float* C_re      = (const float*)d_in[6];
  const float* C_im      = (const float*)d_in[7];
  float* out = (float*)d_out;

  // d_ws usage: 2,756,608 bytes — VERBATIM R9/R11 layout (passed).
  char* ws = (char*)d_ws;
  float2*  carrySeed = (float2*)(ws + 0);        // 1024*256*8 = 2,097,152
  float2*  Lc   = (float2*)(ws + 2097152);       // 2,048
  float2*  LCH  = (float2*)(ws + 2099200);       // 2,048
  ushort*  BnRe = (ushort*)(ws + 2101248);       // 131,072
  ushort*  BnIm = (ushort*)(ws + 2232320);       // 131,072
  ushort*  CRe  = (ushort*)(ws + 2363392);       // 131,072
  ushort*  CIm  = (ushort*)(ws + 2494464);       // 131,072  (end 2,625,536)
  float2*  Lpow = (float2*)(ws + 2625536);       // 64*256*8 = 131,072 (end 2,756,608)

  hipLaunchKernelGGL(k_setup, dim3(NN + 1), dim3(NN), 0, stream,
                     nu_log, theta_log, gamma_log, B_re, B_im, C_re, C_im,
                     Lc, LCH, Lpow, BnRe, BnIm, CRe, CIm);
  hipLaunchKernelGGL(k_carry, dim3(NCHUNK), dim3(256), 0, stream,
                     x, BnRe, BnIm, Lpow, carrySeed);
  hipLaunchKernelGGL(k_seed, dim3(NB), dim3(NN), 0, stream, carrySeed, LCH);
  hipLaunchKernelGGL(k_out, dim3(NCHUNK), dim3(256), 0, stream,
                     x, BnRe, BnIm, Lc, carrySeed, CRe, CIm, Lpow, out);
}